// Round 2
// baseline (111.093 us; speedup 1.0000x reference)
//
#include <hip/hip_runtime.h>

#define NI 12   // input props
#define NR 6    // rules
#define NJ 2    // templates per rule
#define NL 2    // feature width
#define NV 4    // variables

typedef float v2f __attribute__((ext_vector_type(2)));

#define LOG2E 1.4426950408889634f

// Derived-parameter workspace layout (floats), g = r*NJ + j in [0,12):
//   P[g*16 + 0,1]   = A0,A0   ( 2*log2e * w0*t0 )
//   P[g*16 + 2,3]   = A1,A1   ( 2*log2e * w1*t1 )
//   P[g*16 + 4,5]   = W0,W0   ( -log2e * w0 )
//   P[g*16 + 6,7]   = W1,W1   ( -log2e * w1 )
//   P[g*16 + 8,9]   = Cn,Cn   ( -log2e * (w0*t0^2 + w1*t1^2) )
//   P[g*16 +10..13] = m00,m01,m10,m11
//   P[192 + r*2+l]  = C[r][l]
__global__ __launch_bounds__(64) void
abstraction_params(const float* __restrict__ templates,
                   const float* __restrict__ gammas,
                   const float* __restrict__ body_W,
                   const float* __restrict__ body_b,
                   const float* __restrict__ head_W,
                   const float* __restrict__ head_b,
                   float* __restrict__ P) {
    const int t = threadIdx.x;
    if (t < NR * NJ) {
        const int g = t, r = g >> 1, j = g & 1;
        float g0 = fminf(fmaxf(gammas[g * NL + 0], 0.f), 1.f);
        float g1 = fminf(fmaxf(gammas[g * NL + 1], 0.f), 1.f);
        float w0 = 1.f - g0, w1 = 1.f - g1;
        float t0 = templates[g * NL + 0], t1 = templates[g * NL + 1];
        float A0 = 2.f * LOG2E * w0 * t0, A1 = 2.f * LOG2E * w1 * t1;
        float W0 = -LOG2E * w0, W1 = -LOG2E * w1;
        float Cn = -LOG2E * (w0 * t0 * t0 + w1 * t1 * t1);
        float* rec = P + g * 16;
        rec[0] = A0; rec[1] = A0;
        rec[2] = A1; rec[3] = A1;
        rec[4] = W0; rec[5] = W0;
        rec[6] = W1; rec[7] = W1;
        rec[8] = Cn; rec[9] = Cn;
        #pragma unroll
        for (int l = 0; l < NL; ++l) {
            #pragma unroll
            for (int lp = 0; lp < NL; ++lp) {
                float acc = 0.f;
                #pragma unroll
                for (int v = 0; v < NV; ++v)
                    acc = fmaf(head_W[(r * NL + l) * NV + v],
                               body_W[((r * NJ + j) * NV + v) * NL + lp], acc);
                rec[10 + l * 2 + lp] = acc;
            }
        }
        rec[14] = 0.f; rec[15] = 0.f;
    } else if (t >= 32 && t < 32 + NR * NL) {
        const int idx = t - 32, r = idx >> 1, l = idx & 1;
        float acc = head_b[r * NL + l];
        #pragma unroll
        for (int v = 0; v < NV; ++v)
            acc = fmaf(head_W[(r * NL + l) * NV + v],
                       body_b[(r * NJ + 0) * NV + v] + body_b[(r * NJ + 1) * NV + v],
                       acc);
        P[192 + idx] = acc;
    }
}

// Main kernel. One element per thread, but ALL global traffic is staged
// through LDS so every global load/store instruction is perfectly coalesced
// (16B/lane, lane-contiguous). LDS records padded to strides coprime with the
// 8 quad-banks (7 quads in, 5 quads out) -> conflict-free b128 access.
__global__ __launch_bounds__(256) void
abstraction_main(const float* __restrict__ feat,
                 const float* __restrict__ P,
                 float* __restrict__ out, int B) {
    __shared__ float4 sQ[256 * 7];   // 28672 B, reused for out-staging

    const int t = threadIdx.x;
    const int blk = blockIdx.x;
    const int base = blk * 256;
    const bool full = (base + 256 <= B);

    float f0[NI], f1[NI];

    if (full) {
        // ---- coalesced load: 1536 float4, flat index k*256+t ----
        const float4* fin = (const float4*)feat + (size_t)base * 6;
        #pragma unroll
        for (int k = 0; k < 6; ++k) {
            int flat = k * 256 + t;
            float4 v = fin[flat];
            int e = (flat * 10923) >> 16;   // flat/6  (exact for flat<32768)
            int q = flat - 6 * e;
            sQ[e * 7 + q] = v;              // quad-bank (7e+q)&7: conflict-free-ish
        }
        __syncthreads();
        #pragma unroll
        for (int q = 0; q < 6; ++q) {
            float4 v = sQ[t * 7 + q];       // quad-bank (7t+q)&7: conflict-free
            f0[2 * q + 0] = v.x; f1[2 * q + 0] = v.y;
            f0[2 * q + 1] = v.z; f1[2 * q + 1] = v.w;
        }
    } else {
        if (base + t < B) {
            const float4* fp = (const float4*)(feat + (size_t)(base + t) * (NI * NL));
            #pragma unroll
            for (int k = 0; k < 6; ++k) {
                float4 v = fp[k];
                f0[2 * k + 0] = v.x; f1[2 * k + 0] = v.y;
                f0[2 * k + 1] = v.z; f1[2 * k + 1] = v.w;
            }
        }
    }

    // ---- compute (params via wave-uniform scalar-cache loads) ----
    float o[NR * NL];
    #pragma unroll
    for (int r = 0; r < NR; ++r) {
        float o0 = P[192 + r * 2 + 0];
        float o1 = P[192 + r * 2 + 1];
        #pragma unroll
        for (int j = 0; j < NJ; ++j) {
            const float* __restrict__ rec = P + (r * NJ + j) * 16;
            const v2f A0 = *(const v2f*)(rec + 0);
            const v2f A1 = *(const v2f*)(rec + 2);
            const v2f W0 = *(const v2f*)(rec + 4);
            const v2f W1 = *(const v2f*)(rec + 6);
            const v2f Cn = *(const v2f*)(rec + 8);
            v2f den = 0.f, a0 = 0.f, a1 = 0.f;
            #pragma unroll
            for (int i = 0; i < NI; i += 2) {
                v2f X0 = { f0[i], f0[i + 1] };
                v2f X1 = { f1[i], f1[i + 1] };
                v2f n = __builtin_elementwise_fma(X0, __builtin_elementwise_fma(W0, X0, A0), Cn);
                n = __builtin_elementwise_fma(X1, __builtin_elementwise_fma(W1, X1, A1), n);
                v2f p = { __builtin_amdgcn_exp2f(n.x), __builtin_amdgcn_exp2f(n.y) };
                den += p;
                a0 = __builtin_elementwise_fma(p, X0, a0);
                a1 = __builtin_elementwise_fma(p, X1, a1);
            }
            float d = den.x + den.y;
            float rinv = __builtin_amdgcn_rcpf(d);
            float s0 = (a0.x + a0.y) * rinv;
            float s1 = (a1.x + a1.y) * rinv;
            o0 = fmaf(s0, rec[10], o0); o0 = fmaf(s1, rec[11], o0);
            o1 = fmaf(s0, rec[12], o1); o1 = fmaf(s1, rec[13], o1);
        }
        o[r * 2 + 0] = o0;
        o[r * 2 + 1] = o1;
    }

    if (full) {
        __syncthreads();   // all sQ reads done before overwrite
        sQ[t * 5 + 0] = make_float4(o[0], o[1], o[2], o[3]);     // quad-bank (5t+o)&7
        sQ[t * 5 + 1] = make_float4(o[4], o[5], o[6], o[7]);
        sQ[t * 5 + 2] = make_float4(o[8], o[9], o[10], o[11]);
        __syncthreads();
        // ---- coalesced store: 768 float4, flat index k*256+t ----
        float4* fout = (float4*)out + (size_t)base * 3;
        #pragma unroll
        for (int k = 0; k < 3; ++k) {
            int flat = k * 256 + t;
            int e = (flat * 21846) >> 16;   // flat/3 (exact for this range)
            int oo = flat - 3 * e;
            fout[flat] = sQ[e * 5 + oo];
        }
    } else {
        if (base + t < B) {
            float4* op = (float4*)(out + (size_t)(base + t) * (NR * NL));
            op[0] = make_float4(o[0], o[1], o[2], o[3]);
            op[1] = make_float4(o[4], o[5], o[6], o[7]);
            op[2] = make_float4(o[8], o[9], o[10], o[11]);
        }
    }
}

extern "C" void kernel_launch(void* const* d_in, const int* in_sizes, int n_in,
                              void* d_out, int out_size, void* d_ws, size_t ws_size,
                              hipStream_t stream) {
    (void)n_in; (void)out_size; (void)ws_size;
    const float* feat      = (const float*)d_in[0];
    const float* templates = (const float*)d_in[1];
    const float* gammas    = (const float*)d_in[2];
    const float* body_W    = (const float*)d_in[3];
    const float* body_b    = (const float*)d_in[4];
    const float* head_W    = (const float*)d_in[5];
    const float* head_b    = (const float*)d_in[6];
    float* out = (float*)d_out;
    float* P   = (float*)d_ws;   // 204 floats used

    int B = in_sizes[0] / (NI * NL);
    int blocks = (B + 255) / 256;

    hipLaunchKernelGGL(abstraction_params, dim3(1), dim3(64), 0, stream,
                       templates, gammas, body_W, body_b, head_W, head_b, P);
    hipLaunchKernelGGL(abstraction_main, dim3(blocks), dim3(256), 0, stream,
                       feat, P, out, B);
}

// Round 3
// 106.377 us; speedup vs baseline: 1.0443x; 1.0443x over previous
//
#include <hip/hip_runtime.h>

#define NI 12   // input props
#define NR 6    // rules
#define NJ 2    // templates per rule
#define NL 2    // feature width
#define NV 4    // variables

typedef float v2f __attribute__((ext_vector_type(2)));

// Single fused kernel (best-measured variant, R0 = 109.0 µs).
// Per-block, the first waves compute the 120 derived parameters into LDS
// (redundant across blocks, ~nothing), then every thread handles one batch
// element. R1/R2 established: param path (LDS vs scalar-cache) and global
// access pattern (96B-stride vs LDS-staged coalesced) are both perf-neutral —
// the kernel is BW-saturated at ~13-16µs vs a 12.5µs mandatory-traffic floor,
// and total dur_us is dominated by 84µs of fixed harness re-poison fills.
// Therefore: minimize launches (one kernel) and staging overhead (none).
//
// Derived params:
//  sG[g*5+..] per (r,j) g=r*2+j: A0,A1,W0,W1,Cn with
//     n_i = x0*(W0*x0+A0) + x1*(W1*x1+A1) + Cn   (== -log2e * match_score)
//  sM[((r*2+l)*2+j)*2+lp] = sum_v head_W[r,l,v]*body_W[r,j,v,lp]
//  sC[r*2+l] = head_b[r,l] + sum_v head_W[r,l,v]*(body_b[r,0,v]+body_b[r,1,v])

__global__ __launch_bounds__(256) void
abstraction_fused(const float* __restrict__ feat,
                  const float* __restrict__ templates,
                  const float* __restrict__ gammas,
                  const float* __restrict__ body_W,
                  const float* __restrict__ body_b,
                  const float* __restrict__ head_W,
                  const float* __restrict__ head_b,
                  float* __restrict__ out, int B) {
    __shared__ float sG[NR * NJ * 5];
    __shared__ float sM[NR * NL * NJ * NL];
    __shared__ float sC[NR * NL];

    const int t = threadIdx.x;
    const float LOG2E = 1.4426950408889634f;

    if (t < NR * NJ) {
        // group params for g = t
        const int g = t;
        float g0 = fminf(fmaxf(gammas[g * NL + 0], 0.f), 1.f);
        float g1 = fminf(fmaxf(gammas[g * NL + 1], 0.f), 1.f);
        float w0 = 1.f - g0, w1 = 1.f - g1;
        float t0 = templates[g * NL + 0], t1 = templates[g * NL + 1];
        float wt0 = w0 * t0, wt1 = w1 * t1;
        float c0 = wt0 * t0 + wt1 * t1;
        sG[g * 5 + 0] = 2.f * LOG2E * wt0;
        sG[g * 5 + 1] = 2.f * LOG2E * wt1;
        sG[g * 5 + 2] = -LOG2E * w0;
        sG[g * 5 + 3] = -LOG2E * w1;
        sG[g * 5 + 4] = -LOG2E * c0;
    } else if (t >= 64 && t < 64 + NR * NL) {
        // head constants C[r][l]
        const int idx = t - 64;
        const int r = idx >> 1, l = idx & 1;
        float acc = head_b[r * NL + l];
        #pragma unroll
        for (int v = 0; v < NV; ++v) {
            float bs = body_b[(r * NJ + 0) * NV + v] + body_b[(r * NJ + 1) * NV + v];
            acc = fmaf(head_W[(r * NL + l) * NV + v], bs, acc);
        }
        sC[idx] = acc;
    } else if (t >= 128 && t < 128 + NR * NL * NJ * NL) {
        // fused matrix M[r][l][j][lp]
        const int idx = t - 128;
        const int lp = idx & 1, j = (idx >> 1) & 1, l = (idx >> 2) & 1, r = idx >> 3;
        float acc = 0.f;
        #pragma unroll
        for (int v = 0; v < NV; ++v)
            acc = fmaf(head_W[(r * NL + l) * NV + v],
                       body_W[((r * NJ + j) * NV + v) * NL + lp], acc);
        sM[idx] = acc;
    }
    __syncthreads();

    const int b = blockIdx.x * blockDim.x + t;
    if (b >= B) return;

    // 24 features: 6 x float4 (16B/lane). Split by l-component.
    const float4* fp = (const float4*)(feat + (size_t)b * (NI * NL));
    float f0[NI], f1[NI];
    #pragma unroll
    for (int k = 0; k < 6; ++k) {
        float4 v = fp[k];
        f0[2 * k + 0] = v.x; f1[2 * k + 0] = v.y;
        f0[2 * k + 1] = v.z; f1[2 * k + 1] = v.w;
    }

    float o[NR * NL];
    #pragma unroll
    for (int r = 0; r < NR; ++r) {
        float o0 = sC[r * 2 + 0];
        float o1 = sC[r * 2 + 1];
        #pragma unroll
        for (int j = 0; j < NJ; ++j) {
            const int g = r * NJ + j;
            const v2f A0 = sG[g * 5 + 0];
            const v2f A1 = sG[g * 5 + 1];
            const v2f W0 = sG[g * 5 + 2];
            const v2f W1 = sG[g * 5 + 3];
            const v2f Cn = sG[g * 5 + 4];
            v2f den = 0.f, a0 = 0.f, a1 = 0.f;
            #pragma unroll
            for (int i = 0; i < NI; i += 2) {
                v2f X0 = { f0[i], f0[i + 1] };
                v2f X1 = { f1[i], f1[i + 1] };
                // n = X0*(W0*X0+A0) + X1*(W1*X1+A1) + Cn  (packed fp32)
                v2f n = __builtin_elementwise_fma(X0, __builtin_elementwise_fma(W0, X0, A0), Cn);
                n = __builtin_elementwise_fma(X1, __builtin_elementwise_fma(W1, X1, A1), n);
                // args in [-1.8, 0]: exp2 directly, no max-subtraction needed
                v2f p = { __builtin_amdgcn_exp2f(n.x), __builtin_amdgcn_exp2f(n.y) };
                den += p;
                a0 = __builtin_elementwise_fma(p, X0, a0);
                a1 = __builtin_elementwise_fma(p, X1, a1);
            }
            float d = den.x + den.y;
            float rinv = __builtin_amdgcn_rcpf(d);
            float s0 = (a0.x + a0.y) * rinv;
            float s1 = (a1.x + a1.y) * rinv;
            const float m00 = sM[((r * 2 + 0) * 2 + j) * 2 + 0];
            const float m01 = sM[((r * 2 + 0) * 2 + j) * 2 + 1];
            const float m10 = sM[((r * 2 + 1) * 2 + j) * 2 + 0];
            const float m11 = sM[((r * 2 + 1) * 2 + j) * 2 + 1];
            o0 = fmaf(s0, m00, o0); o0 = fmaf(s1, m01, o0);
            o1 = fmaf(s0, m10, o1); o1 = fmaf(s1, m11, o1);
        }
        o[r * 2 + 0] = o0;
        o[r * 2 + 1] = o1;
    }

    float4* op = (float4*)(out + (size_t)b * (NR * NL));
    op[0] = make_float4(o[0], o[1], o[2], o[3]);
    op[1] = make_float4(o[4], o[5], o[6], o[7]);
    op[2] = make_float4(o[8], o[9], o[10], o[11]);
}

extern "C" void kernel_launch(void* const* d_in, const int* in_sizes, int n_in,
                              void* d_out, int out_size, void* d_ws, size_t ws_size,
                              hipStream_t stream) {
    (void)n_in; (void)out_size; (void)d_ws; (void)ws_size;
    const float* feat      = (const float*)d_in[0];
    const float* templates = (const float*)d_in[1];
    const float* gammas    = (const float*)d_in[2];
    const float* body_W    = (const float*)d_in[3];
    const float* body_b    = (const float*)d_in[4];
    const float* head_W    = (const float*)d_in[5];
    const float* head_b    = (const float*)d_in[6];
    float* out = (float*)d_out;

    int B = in_sizes[0] / (NI * NL);
    int blocks = (B + 255) / 256;
    hipLaunchKernelGGL(abstraction_fused, dim3(blocks), dim3(256), 0, stream,
                       feat, templates, gammas, body_W, body_b, head_W, head_b,
                       out, B);
}